// Round 1
// baseline (659.946 us; speedup 1.0000x reference)
//
#include <hip/hip_runtime.h>
#include <hip/hip_bf16.h>

#define M_ENS 8
#define BATCH 16384
#define HIST 5
#define LDIM 384
#define HID 512
#define NHL 2
#define DIN 1925
#define KPAD 1984   // DIN padded to multiple of 64

typedef unsigned short u16;
typedef unsigned int u32;
typedef __attribute__((ext_vector_type(8))) short bf16x8;
typedef __attribute__((ext_vector_type(4))) float f32x4;

__device__ __forceinline__ u16 f2b(float f) {
    u32 u = __builtin_bit_cast(u32, f);
    u32 r = (u + 0x7fffu + ((u >> 16) & 1u)) >> 16;
    return (u16)r;
}

// ---------------- prep: build padded bf16 x = concat(z_hist, a_hist) ----------------
__global__ void build_x(const float* __restrict__ z, const float* __restrict__ a,
                        u16* __restrict__ xp) {
    int idx = blockIdx.x * 256 + threadIdx.x;          // each thread: 2 elements
    int b = idx / (KPAD / 2);
    int k2 = (idx % (KPAD / 2)) * 2;
    if (b >= BATCH) return;
    u32 packed = 0;
#pragma unroll
    for (int j = 0; j < 2; ++j) {
        int k = k2 + j;
        float v = 0.f;
        if (k < HIST * LDIM) v = z[(size_t)b * (HIST * LDIM) + k];
        else if (k < DIN)    v = a[b * HIST + (k - HIST * LDIM)];
        packed |= ((u32)f2b(v)) << (16 * j);
    }
    *(u32*)(&xp[(size_t)b * KPAD + k2]) = packed;
}

// ---------------- prep: fp32 [R][C] -> bf16 [C][Rp] transpose+convert (zero-pad rows>=R) ----
__global__ void transpose_cvt(const float* __restrict__ in, u16* __restrict__ out,
                              int R, int C, int Rp) {
    __shared__ float tile[32][33];
    const float* inb = in + (size_t)blockIdx.z * R * C;
    u16* outb = out + (size_t)blockIdx.z * C * Rp;
    int r0 = blockIdx.x * 32, c0 = blockIdx.y * 32;
    int tx = threadIdx.x & 31, ty = threadIdx.x >> 5;   // 256 threads: ty 0..7
#pragma unroll
    for (int i = 0; i < 32; i += 8) {
        int r = r0 + ty + i;
        float v = 0.f;
        if (r < R) v = inb[(size_t)r * C + c0 + tx];
        tile[ty + i][tx] = v;
    }
    __syncthreads();
#pragma unroll
    for (int i = 0; i < 32; i += 8) {
        outb[(size_t)(c0 + ty + i) * Rp + r0 + tx] = f2b(tile[tx][ty + i]);
    }
}

// ---------------- prep: fold BN into scale/shift:  y = matmul*s + t ----------------
__global__ void make_tables(const float* __restrict__ bh, const float* __restrict__ gamma,
                            const float* __restrict__ beta, const float* __restrict__ rmean,
                            const float* __restrict__ rvar, float* __restrict__ s,
                            float* __restrict__ t, int n) {
    int i = blockIdx.x * 256 + threadIdx.x;
    if (i >= n) return;
    float inv = rsqrtf(rvar[i] + 1e-5f);
    float sc = gamma[i] * inv;
    s[i] = sc;
    t[i] = (bh[i] - rmean[i]) * sc + beta[i];
}

// ---------------- main MFMA GEMM: C[128x128 tile] = A[M,K] * Bt[N,K]^T ----------------
// MODE 0: h = relu(acc + Tv[n])            -> bf16, row stride HID
// MODE 1: h = relu(acc*Sv[n] + Tv[n])      -> bf16, row stride HID
// MODE 2: o = acc + Tv[n] + z_last[row,n]  -> fp32, row stride LDIM
template <int MODE>
__global__ __launch_bounds__(256, 2) void gemm_bt(
    const u16* __restrict__ A, size_t aStride, int lda,
    const u16* __restrict__ Bt, size_t bStride,
    const float* __restrict__ Sv, const float* __restrict__ Tv, int ptStride,
    u16* __restrict__ Ho, size_t hStride,
    float* __restrict__ Fo, size_t fStride,
    const float* __restrict__ Zres,
    int K, int m0) {
    __shared__ u16 As[128 * 64];
    __shared__ u16 Bs[128 * 64];

    const int tid = threadIdx.x;
    const int lane = tid & 63;
    const int wid = tid >> 6;
    const int wr = (wid >> 1) * 64;     // wave row offset in tile
    const int wc = (wid & 1) * 64;      // wave col offset in tile
    const int z = blockIdx.z;
    const int rowBase = blockIdx.x * 128;
    const int colBase = blockIdx.y * 128;

    const u16* Ab = A + (size_t)z * aStride;
    const u16* Bb = Bt + (size_t)z * bStride;

    f32x4 acc[4][4] = {};

    // per-thread swizzled LDS read offsets (bytes) for the 4 frags of each operand
    int aoff[4], boff[4];
#pragma unroll
    for (int f = 0; f < 4; ++f) {
        int ar = wr + f * 16 + (lane & 15);
        aoff[f] = (ar * 128 + ((lane >> 4) * 16)) ^ ((ar & 7) << 4);
        int br = wc + f * 16 + (lane & 15);
        boff[f] = (br * 128 + ((lane >> 4) * 16)) ^ ((br & 7) << 4);
    }

    for (int k0 = 0; k0 < K; k0 += 64) {
        // stage A and Bt tiles [128 rows][64 K] via global_load_lds, 16B granules.
        // LDS dest is linear (wave-uniform base + lane*16); global source is
        // pre-swizzled: granule gc of row r sources gc ^ (r&7)  (rule #21).
#pragma unroll
        for (int i = 0; i < 4; ++i) {
            int gg = i * 256 + tid;             // granule index 0..1023
            int row = gg >> 3, gc = gg & 7;
            const u16* srcA = Ab + (size_t)(rowBase + row) * lda + k0 + ((gc ^ (row & 7)) << 3);
            __builtin_amdgcn_global_load_lds(
                (const __attribute__((address_space(1))) void*)srcA,
                (__attribute__((address_space(3))) void*)(As + gg * 8), 16, 0, 0);
            const u16* srcB = Bb + (size_t)(colBase + row) * K + k0 + ((gc ^ (row & 7)) << 3);
            __builtin_amdgcn_global_load_lds(
                (const __attribute__((address_space(1))) void*)srcB,
                (__attribute__((address_space(3))) void*)(Bs + gg * 8), 16, 0, 0);
        }
        __syncthreads();
#pragma unroll
        for (int kk = 0; kk < 2; ++kk) {
            bf16x8 af[4], bfr[4];
#pragma unroll
            for (int f = 0; f < 4; ++f) {
                af[f]  = *(const bf16x8*)((const char*)As + (aoff[f] ^ (kk << 6)));
                bfr[f] = *(const bf16x8*)((const char*)Bs + (boff[f] ^ (kk << 6)));
            }
#pragma unroll
            for (int i = 0; i < 4; ++i)
#pragma unroll
                for (int j = 0; j < 4; ++j)
                    acc[i][j] = __builtin_amdgcn_mfma_f32_16x16x32_bf16(af[i], bfr[j], acc[i][j], 0, 0, 0);
        }
        __syncthreads();
    }

    // epilogue: C/D layout col = lane&15, row = (lane>>4)*4 + q   [m89-verified]
    const int mg = m0 + z;
#pragma unroll
    for (int i = 0; i < 4; ++i) {
        int rbase = rowBase + wr + i * 16 + ((lane >> 4) << 2);
#pragma unroll
        for (int j = 0; j < 4; ++j) {
            int n = colBase + wc + j * 16 + (lane & 15);
            if (MODE == 0) {
                float bias = Tv[(size_t)mg * ptStride + n];
                u16* H = Ho + (size_t)z * hStride;
#pragma unroll
                for (int q = 0; q < 4; ++q) {
                    float v = acc[i][j][q] + bias;
                    v = v > 0.f ? v : 0.f;
                    H[(size_t)(rbase + q) * HID + n] = f2b(v);
                }
            } else if (MODE == 1) {
                float sc = Sv[(size_t)mg * ptStride + n];
                float tt = Tv[(size_t)mg * ptStride + n];
                u16* H = Ho + (size_t)z * hStride;
#pragma unroll
                for (int q = 0; q < 4; ++q) {
                    float v = acc[i][j][q] * sc + tt;
                    v = v > 0.f ? v : 0.f;
                    H[(size_t)(rbase + q) * HID + n] = f2b(v);
                }
            } else {
                float bias = Tv[(size_t)mg * ptStride + n];
                float* F = Fo + (size_t)z * fStride;
#pragma unroll
                for (int q = 0; q < 4; ++q) {
                    int b = rbase + q;
                    float v = acc[i][j][q] + bias + Zres[(size_t)b * (HIST * LDIM) + (HIST - 1) * LDIM + n];
                    F[(size_t)b * LDIM + n] = v;
                }
            }
        }
    }
}

extern "C" void kernel_launch(void* const* d_in, const int* in_sizes, int n_in,
                              void* d_out, int out_size, void* d_ws, size_t ws_size,
                              hipStream_t stream) {
    const float* z_hist = (const float*)d_in[0];
    const float* a_hist = (const float*)d_in[1];
    const float* W1    = (const float*)d_in[2];
    const float* b1    = (const float*)d_in[3];
    const float* Wh    = (const float*)d_in[4];
    const float* bh    = (const float*)d_in[5];
    const float* gamma = (const float*)d_in[6];
    const float* beta  = (const float*)d_in[7];
    const float* rmean = (const float*)d_in[8];
    const float* rvar  = (const float*)d_in[9];
    const float* W3    = (const float*)d_in[10];
    const float* b3    = (const float*)d_in[11];
    float* out = (float*)d_out;

    char* ws = (char*)d_ws;
    size_t off = 0;
    auto alloc = [&](size_t bytes) {
        void* p = ws + off;
        off = (off + bytes + 255) & ~(size_t)255;
        return p;
    };
    u16* xp  = (u16*)alloc((size_t)BATCH * KPAD * 2);
    u16* W1t = (u16*)alloc((size_t)M_ENS * HID * KPAD * 2);
    u16* Wht = (u16*)alloc((size_t)NHL * M_ENS * HID * HID * 2);
    u16* W3t = (u16*)alloc((size_t)M_ENS * LDIM * HID * 2);
    float* stab = (float*)alloc((size_t)NHL * M_ENS * HID * 4);
    float* ttab = (float*)alloc((size_t)NHL * M_ENS * HID * 4);
    size_t fixed = off;
    size_t hFull = (size_t)M_ENS * BATCH * HID * 2;
    int MC = (fixed + 2 * hFull <= ws_size) ? M_ENS : 1;
    u16* h0 = (u16*)alloc((size_t)MC * BATCH * HID * 2);
    u16* h1 = (u16*)alloc((size_t)MC * BATCH * HID * 2);

    // ---- prep ----
    {
        int total = BATCH * KPAD / 2;
        build_x<<<(total + 255) / 256, 256, 0, stream>>>(z_hist, a_hist, xp);
        dim3 g1(KPAD / 32, HID / 32, M_ENS);
        transpose_cvt<<<g1, 256, 0, stream>>>(W1, W1t, DIN, HID, KPAD);
        dim3 g2(HID / 32, HID / 32, NHL * M_ENS);
        transpose_cvt<<<g2, 256, 0, stream>>>(Wh, Wht, HID, HID, HID);
        dim3 g3(HID / 32, LDIM / 32, M_ENS);
        transpose_cvt<<<g3, 256, 0, stream>>>(W3, W3t, HID, LDIM, HID);
        int n = NHL * M_ENS * HID;
        make_tables<<<(n + 255) / 256, 256, 0, stream>>>(bh, gamma, beta, rmean, rvar, stab, ttab, n);
    }

    // ---- 4 GEMM layers, batched over ensemble in chunks of MC ----
    for (int m0 = 0; m0 < M_ENS; m0 += MC) {
        dim3 grid(BATCH / 128, HID / 128, MC);
        // layer 1: x [B,KPAD] (shared across ensemble) * W1t[m] -> h0  (relu + b1)
        gemm_bt<0><<<grid, 256, 0, stream>>>(
            xp, 0, KPAD,
            W1t + (size_t)m0 * HID * KPAD, (size_t)HID * KPAD,
            nullptr, b1, HID,
            h0, (size_t)BATCH * HID, nullptr, 0, nullptr,
            KPAD, m0);
        // hidden layers with folded BN
        for (int l = 0; l < NHL; ++l) {
            u16* hin = l ? h1 : h0;
            u16* hout = l ? h0 : h1;
            gemm_bt<1><<<grid, 256, 0, stream>>>(
                hin, (size_t)BATCH * HID, HID,
                Wht + ((size_t)l * M_ENS + m0) * HID * HID, (size_t)HID * HID,
                stab + (size_t)l * M_ENS * HID, ttab + (size_t)l * M_ENS * HID, HID,
                hout, (size_t)BATCH * HID, nullptr, 0, nullptr,
                HID, m0);
        }
        // output layer: h0 * W3t[m] + b3 + z_last -> out (fp32)
        dim3 gridO(BATCH / 128, LDIM / 128, MC);
        gemm_bt<2><<<gridO, 256, 0, stream>>>(
            h0, (size_t)BATCH * HID, HID,
            W3t + (size_t)m0 * LDIM * HID, (size_t)LDIM * HID,
            nullptr, b3, LDIM,
            nullptr, 0,
            out + (size_t)m0 * BATCH * LDIM, (size_t)BATCH * LDIM,
            z_hist,
            HID, m0);
    }
}

// Round 2
// 634.694 us; speedup vs baseline: 1.0398x; 1.0398x over previous
//
#include <hip/hip_runtime.h>
#include <hip/hip_bf16.h>

#define M_ENS 8
#define BATCH 16384
#define HIST 5
#define LDIM 384
#define HID 512
#define NHL 2
#define DIN 1925
#define KP 2048   // DIN padded to multiple of 128 (even number of 64-K-tiles)

typedef unsigned short u16;
typedef unsigned int u32;
typedef __attribute__((ext_vector_type(8))) short bf16x8;
typedef __attribute__((ext_vector_type(4))) float f32x4;

__device__ __forceinline__ u16 f2b(float f) {
    u32 u = __builtin_bit_cast(u32, f);
    u32 r = (u + 0x7fffu + ((u >> 16) & 1u)) >> 16;
    return (u16)r;
}

// ---------------- prep: build padded bf16 x = concat(z_hist, a_hist) ----------------
__global__ void build_x(const float* __restrict__ z, const float* __restrict__ a,
                        u16* __restrict__ xp) {
    int idx = blockIdx.x * 256 + threadIdx.x;          // each thread: 2 elements
    int b = idx / (KP / 2);
    int k2 = (idx % (KP / 2)) * 2;
    if (b >= BATCH) return;
    u32 packed = 0;
#pragma unroll
    for (int j = 0; j < 2; ++j) {
        int k = k2 + j;
        float v = 0.f;
        if (k < HIST * LDIM) v = z[(size_t)b * (HIST * LDIM) + k];
        else if (k < DIN)    v = a[b * HIST + (k - HIST * LDIM)];
        packed |= ((u32)f2b(v)) << (16 * j);
    }
    *(u32*)(&xp[(size_t)b * KP + k2]) = packed;
}

// ---------------- prep: fp32 [R][C] -> bf16 [C][Rp] transpose+convert ----------------
__global__ void transpose_cvt(const float* __restrict__ in, u16* __restrict__ out,
                              int R, int C, int Rp) {
    __shared__ float tile[32][33];
    const float* inb = in + (size_t)blockIdx.z * R * C;
    u16* outb = out + (size_t)blockIdx.z * C * Rp;
    int r0 = blockIdx.x * 32, c0 = blockIdx.y * 32;
    int tx = threadIdx.x & 31, ty = threadIdx.x >> 5;
#pragma unroll
    for (int i = 0; i < 32; i += 8) {
        int r = r0 + ty + i;
        float v = 0.f;
        if (r < R) v = inb[(size_t)r * C + c0 + tx];
        tile[ty + i][tx] = v;
    }
    __syncthreads();
#pragma unroll
    for (int i = 0; i < 32; i += 8) {
        outb[(size_t)(c0 + ty + i) * Rp + r0 + tx] = f2b(tile[tx][ty + i]);
    }
}

// ---------------- prep: fold BN into scale/shift ----------------
__global__ void make_tables(const float* __restrict__ bh, const float* __restrict__ gamma,
                            const float* __restrict__ beta, const float* __restrict__ rmean,
                            const float* __restrict__ rvar, float* __restrict__ s,
                            float* __restrict__ t, int n) {
    int i = blockIdx.x * 256 + threadIdx.x;
    if (i >= n) return;
    float inv = rsqrtf(rvar[i] + 1e-5f);
    float sc = gamma[i] * inv;
    s[i] = sc;
    t[i] = (bh[i] - rmean[i]) * sc + beta[i];
}

// =====================================================================================
// 8-phase 256x256 GEMM (T3+T4 counted vmcnt, T5 setprio), BK=64, 8 waves (2M x 4N).
// LDS 128 KiB: [parity 2][op A/B][half 2][128 rows][64 K] bf16, granule-XOR swizzled.
// MODE 0: fused layer1  C[B, 4096] = x[B,KP] * W1t^T, relu(+b1), write h0[m][B][512]
// MODE 1: hidden        per-model (from swizzle) h_out = relu(h_in*Wh^T * s + t)
// =====================================================================================
#define BARRIER asm volatile("s_barrier" ::: "memory")

template <int MODE>
__global__ __launch_bounds__(512, 2) void gemm8p(
    const u16* __restrict__ A, const u16* __restrict__ Bw,
    const float* __restrict__ Sv, const float* __restrict__ Tv,
    u16* __restrict__ Ho, int K) {
    extern __shared__ char smem[];
    const int tid = threadIdx.x;
    const int lane = tid & 63;
    const int wid = tid >> 6;
    const int wm = wid >> 2;          // 0..1 (M half of tile)
    const int wn = wid & 3;           // 0..3 (N quarter of tile)

    // bijective XCD swizzle (nwg % 8 == 0): contiguous chunk per XCD
    const int nwg = gridDim.x;
    const int swz = (blockIdx.x & 7) * (nwg >> 3) + (blockIdx.x >> 3);

    int rowT, colT, mI;
    const u16 *Ab, *Bb;
    int lda, ldb;
    if (MODE == 0) {
        rowT = swz >> 4; colT = swz & 15;           // 64 row-tiles x 16 col-tiles
        Ab = A; lda = KP;
        Bb = Bw + (size_t)colT * 256 * KP; ldb = KP;
        mI = 0;
    } else {
        mI = swz >> 7;                               // one model per 128-block chunk
        int rem = swz & 127;
        rowT = rem >> 1; colT = rem & 1;             // 64 x 2
        Ab = A + (size_t)mI * BATCH * HID; lda = HID;
        Bb = Bw + (size_t)mI * HID * HID + (size_t)colT * 256 * HID; ldb = HID;
    }
    const int rowBase = rowT * 256;
    const int NT = K >> 6;

    // --- staging: one half-tile (128 rows x 64 K) per call; 2 x global_load_lds/thread.
    // LDS dest linear; global source granule pre-swizzled: gc ^ (row&7)  (rule #21).
    auto STAGE = [&](int par, int op, int half, int tk) {
#pragma unroll
        for (int i = 0; i < 2; ++i) {
            int ii = wid * 2 + i;                    // 0..15 (1024B LDS chunks)
            int row = ii * 8 + (lane >> 3);
            int gc = lane & 7;
            const u16* src;
            if (op == 0)
                src = Ab + (size_t)(rowBase + half * 128 + row) * lda + tk * 64 + ((gc ^ (row & 7)) << 3);
            else
                src = Bb + (size_t)(half * 128 + row) * ldb + tk * 64 + ((gc ^ (row & 7)) << 3);
            u16* dst = (u16*)(smem + par * 65536 + op * 32768 + half * 16384) + (size_t)(ii * 64 + lane) * 8;
            __builtin_amdgcn_global_load_lds((const __attribute__((address_space(1))) void*)src,
                                             (__attribute__((address_space(3))) void*)dst, 16, 0, 0);
        }
    };

    // per-thread swizzled ds_read offsets: frag at row r (in half), k-step kk:
    //   byte = r*128 + (((kk*4 + lane>>4) ^ (r&7)) << 4);  r&7 == lane&7 for all frags
    const int laneRow = lane & 15;
    int xg[2];
    xg[0] = (((lane >> 4)) ^ (lane & 7)) << 4;
    xg[1] = ((4 | (lane >> 4)) ^ (lane & 7)) << 4;
#define RDF(base, r, kk) (*(const bf16x8*)((base) + (size_t)(r) * 128 + xg[kk]))

    f32x4 acc[8][4] = {};
    bf16x8 af[4][2], bfr[4][2];
    const int bcol0 = (wn & 1) * 64;    // col base within B half-buffer

    // ---- prologue: B(0), A(0), B(1); wait for K-tile 0's 8 loads (leave B(1)'s 4)
    STAGE(0, 1, 0, 0); STAGE(0, 1, 1, 0);
    STAGE(0, 0, 0, 0); STAGE(0, 0, 1, 0);
    if (NT > 1) { STAGE(1, 1, 0, 1); STAGE(1, 1, 1, 1); }
    asm volatile("s_waitcnt vmcnt(4)" ::: "memory");
    BARRIER;

    for (int T = 0; T < NT; ++T) {
        const int p = T & 1;
        const char* pA = smem + p * 65536 + wm * 16384;
        const char* pB = smem + p * 65536 + 32768 + (wn >> 1) * 16384;

        // ---- phase 0: read A(Mhalf0) + B(Nhalf0); stage A0(T+1); MFMA quad (0,0)
#pragma unroll
        for (int mf = 0; mf < 4; ++mf) {
            af[mf][0] = RDF(pA, mf * 16 + laneRow, 0);
            af[mf][1] = RDF(pA, mf * 16 + laneRow, 1);
        }
#pragma unroll
        for (int nf = 0; nf < 2; ++nf) {
            bfr[nf][0] = RDF(pB, bcol0 + nf * 16 + laneRow, 0);
            bfr[nf][1] = RDF(pB, bcol0 + nf * 16 + laneRow, 1);
        }
        if (T + 1 < NT) STAGE((T + 1) & 1, 0, 0, T + 1);
        BARRIER;
        __builtin_amdgcn_s_setprio(1);
#pragma unroll
        for (int kk = 0; kk < 2; ++kk)
#pragma unroll
            for (int mf = 0; mf < 4; ++mf)
#pragma unroll
                for (int nf = 0; nf < 2; ++nf)
                    acc[mf][nf] = __builtin_amdgcn_mfma_f32_16x16x32_bf16(af[mf][kk], bfr[nf][kk], acc[mf][nf], 0, 0, 0);
        __builtin_amdgcn_s_setprio(0);
        BARRIER;

        // ---- phase 1: read B(Nhalf1); stage A1(T+1); MFMA quad (0,1)
#pragma unroll
        for (int nf = 2; nf < 4; ++nf) {
            bfr[nf][0] = RDF(pB, bcol0 + nf * 16 + laneRow, 0);
            bfr[nf][1] = RDF(pB, bcol0 + nf * 16 + laneRow, 1);
        }
        if (T + 1 < NT) STAGE((T + 1) & 1, 0, 1, T + 1);
        BARRIER;
        __builtin_amdgcn_s_setprio(1);
#pragma unroll
        for (int kk = 0; kk < 2; ++kk)
#pragma unroll
            for (int mf = 0; mf < 4; ++mf)
#pragma unroll
                for (int nf = 2; nf < 4; ++nf)
                    acc[mf][nf] = __builtin_amdgcn_mfma_f32_16x16x32_bf16(af[mf][kk], bfr[nf][kk], acc[mf][nf], 0, 0, 0);
        __builtin_amdgcn_s_setprio(0);
        BARRIER;

        // ---- phase 2: read A(Mhalf1); stage B0(T+2) (slot free after phase 1); quad (1,1)
#pragma unroll
        for (int mf = 0; mf < 4; ++mf) {
            af[mf][0] = RDF(pA, (4 + mf) * 16 + laneRow, 0);
            af[mf][1] = RDF(pA, (4 + mf) * 16 + laneRow, 1);
        }
        if (T + 2 < NT) STAGE(p, 1, 0, T + 2);
        BARRIER;
        __builtin_amdgcn_s_setprio(1);
#pragma unroll
        for (int kk = 0; kk < 2; ++kk)
#pragma unroll
            for (int mf = 0; mf < 4; ++mf)
#pragma unroll
                for (int nf = 2; nf < 4; ++nf)
                    acc[4 + mf][nf] = __builtin_amdgcn_mfma_f32_16x16x32_bf16(af[mf][kk], bfr[nf][kk], acc[4 + mf][nf], 0, 0, 0);
        __builtin_amdgcn_s_setprio(0);
        BARRIER;

        // ---- phase 3: stage B1(T+2); counted vmcnt (next K-tile's 8 loads must land); quad (1,0)
        if (T + 2 < NT) {
            STAGE(p, 1, 1, T + 2);
            asm volatile("s_waitcnt vmcnt(4)" ::: "memory");
        } else {
            asm volatile("s_waitcnt vmcnt(0)" ::: "memory");
        }
        BARRIER;
        __builtin_amdgcn_s_setprio(1);
#pragma unroll
        for (int kk = 0; kk < 2; ++kk)
#pragma unroll
            for (int mf = 0; mf < 4; ++mf)
#pragma unroll
                for (int nf = 0; nf < 2; ++nf)
                    acc[4 + mf][nf] = __builtin_amdgcn_mfma_f32_16x16x32_bf16(af[mf][kk], bfr[nf][kk], acc[4 + mf][nf], 0, 0, 0);
        __builtin_amdgcn_s_setprio(0);
        BARRIER;
    }

    // ---- epilogue: C/D layout col=lane&15, row=(lane>>4)*4+q
#pragma unroll
    for (int mf = 0; mf < 8; ++mf) {
        int row = rowBase + wm * 128 + mf * 16 + ((lane >> 4) << 2);
#pragma unroll
        for (int nf = 0; nf < 4; ++nf) {
            int c = colT * 256 + wn * 64 + nf * 16 + (lane & 15);
            if (MODE == 0) {
                float tb = Tv[c];
                size_t base = (size_t)(c >> 9) * BATCH * HID + (c & 511);
#pragma unroll
                for (int q = 0; q < 4; ++q) {
                    float v = acc[mf][nf][q] + tb;
                    Ho[base + (size_t)(row + q) * HID] = f2b(v > 0.f ? v : 0.f);
                }
            } else {
                float sc = Sv[mI * HID + c], tb = Tv[mI * HID + c];
                u16* H = Ho + (size_t)mI * BATCH * HID;
#pragma unroll
                for (int q = 0; q < 4; ++q) {
                    float v = acc[mf][nf][q] * sc + tb;
                    H[(size_t)(row + q) * HID + c] = f2b(v > 0.f ? v : 0.f);
                }
            }
        }
    }
}

// ---------------- 128x128 m97-structure GEMM (kept for output layer + fallback) -------
template <int MODE>
__global__ __launch_bounds__(256, 2) void gemm_bt(
    const u16* __restrict__ A, size_t aStride, int lda,
    const u16* __restrict__ Bt, size_t bStride,
    const float* __restrict__ Sv, const float* __restrict__ Tv, int ptStride,
    u16* __restrict__ Ho, size_t hStride,
    float* __restrict__ Fo, size_t fStride,
    const float* __restrict__ Zres,
    int K, int m0) {
    __shared__ u16 As[128 * 64];
    __shared__ u16 Bs[128 * 64];

    const int tid = threadIdx.x;
    const int lane = tid & 63;
    const int wid = tid >> 6;
    const int wr = (wid >> 1) * 64;
    const int wc = (wid & 1) * 64;
    const int z = blockIdx.z;
    const int rowBase = blockIdx.x * 128;
    const int colBase = blockIdx.y * 128;

    const u16* Ab = A + (size_t)z * aStride;
    const u16* Bb = Bt + (size_t)z * bStride;

    f32x4 acc[4][4] = {};

    int aoff[4], boff[4];
#pragma unroll
    for (int f = 0; f < 4; ++f) {
        int ar = wr + f * 16 + (lane & 15);
        aoff[f] = (ar * 128 + ((lane >> 4) * 16)) ^ ((ar & 7) << 4);
        int br = wc + f * 16 + (lane & 15);
        boff[f] = (br * 128 + ((lane >> 4) * 16)) ^ ((br & 7) << 4);
    }

    for (int k0 = 0; k0 < K; k0 += 64) {
#pragma unroll
        for (int i = 0; i < 4; ++i) {
            int gg = i * 256 + tid;
            int row = gg >> 3, gc = gg & 7;
            const u16* srcA = Ab + (size_t)(rowBase + row) * lda + k0 + ((gc ^ (row & 7)) << 3);
            __builtin_amdgcn_global_load_lds(
                (const __attribute__((address_space(1))) void*)srcA,
                (__attribute__((address_space(3))) void*)(As + gg * 8), 16, 0, 0);
            const u16* srcB = Bb + (size_t)(colBase + row) * K + k0 + ((gc ^ (row & 7)) << 3);
            __builtin_amdgcn_global_load_lds(
                (const __attribute__((address_space(1))) void*)srcB,
                (__attribute__((address_space(3))) void*)(Bs + gg * 8), 16, 0, 0);
        }
        __syncthreads();
#pragma unroll
        for (int kk = 0; kk < 2; ++kk) {
            bf16x8 af[4], bfr[4];
#pragma unroll
            for (int f = 0; f < 4; ++f) {
                af[f]  = *(const bf16x8*)((const char*)As + (aoff[f] ^ (kk << 6)));
                bfr[f] = *(const bf16x8*)((const char*)Bs + (boff[f] ^ (kk << 6)));
            }
#pragma unroll
            for (int i = 0; i < 4; ++i)
#pragma unroll
                for (int j = 0; j < 4; ++j)
                    acc[i][j] = __builtin_amdgcn_mfma_f32_16x16x32_bf16(af[i], bfr[j], acc[i][j], 0, 0, 0);
        }
        __syncthreads();
    }

    const int mg = m0 + z;
#pragma unroll
    for (int i = 0; i < 4; ++i) {
        int rbase = rowBase + wr + i * 16 + ((lane >> 4) << 2);
#pragma unroll
        for (int j = 0; j < 4; ++j) {
            int n = colBase + wc + j * 16 + (lane & 15);
            if (MODE == 0) {
                float bias = Tv[(size_t)mg * ptStride + n];
                u16* H = Ho + (size_t)z * hStride;
#pragma unroll
                for (int q = 0; q < 4; ++q) {
                    float v = acc[i][j][q] + bias;
                    v = v > 0.f ? v : 0.f;
                    H[(size_t)(rbase + q) * HID + n] = f2b(v);
                }
            } else if (MODE == 1) {
                float sc = Sv[(size_t)mg * ptStride + n];
                float tt = Tv[(size_t)mg * ptStride + n];
                u16* H = Ho + (size_t)z * hStride;
#pragma unroll
                for (int q = 0; q < 4; ++q) {
                    float v = acc[i][j][q] * sc + tt;
                    v = v > 0.f ? v : 0.f;
                    H[(size_t)(rbase + q) * HID + n] = f2b(v);
                }
            } else {
                float bias = Tv[(size_t)mg * ptStride + n];
                float* F = Fo + (size_t)z * fStride;
#pragma unroll
                for (int q = 0; q < 4; ++q) {
                    int b = rbase + q;
                    float v = acc[i][j][q] + bias + Zres[(size_t)b * (HIST * LDIM) + (HIST - 1) * LDIM + n];
                    F[(size_t)b * LDIM + n] = v;
                }
            }
        }
    }
}

extern "C" void kernel_launch(void* const* d_in, const int* in_sizes, int n_in,
                              void* d_out, int out_size, void* d_ws, size_t ws_size,
                              hipStream_t stream) {
    const float* z_hist = (const float*)d_in[0];
    const float* a_hist = (const float*)d_in[1];
    const float* W1    = (const float*)d_in[2];
    const float* b1    = (const float*)d_in[3];
    const float* Wh    = (const float*)d_in[4];
    const float* bh    = (const float*)d_in[5];
    const float* gamma = (const float*)d_in[6];
    const float* beta  = (const float*)d_in[7];
    const float* rmean = (const float*)d_in[8];
    const float* rvar  = (const float*)d_in[9];
    const float* W3    = (const float*)d_in[10];
    const float* b3    = (const float*)d_in[11];
    float* out = (float*)d_out;

    char* ws = (char*)d_ws;
    size_t off = 0;
    auto alloc = [&](size_t bytes) {
        void* p = ws + off;
        off = (off + bytes + 255) & ~(size_t)255;
        return p;
    };
    u16* xp  = (u16*)alloc((size_t)BATCH * KP * 2);
    u16* W1t = (u16*)alloc((size_t)M_ENS * HID * KP * 2);
    u16* Wht = (u16*)alloc((size_t)NHL * M_ENS * HID * HID * 2);
    u16* W3t = (u16*)alloc((size_t)M_ENS * LDIM * HID * 2);
    float* stab = (float*)alloc((size_t)NHL * M_ENS * HID * 4);
    float* ttab = (float*)alloc((size_t)NHL * M_ENS * HID * 4);
    size_t fixed = off;
    size_t hFull = (size_t)M_ENS * BATCH * HID * 2;
    bool full = (fixed + 2 * hFull <= ws_size);
    int MC = full ? M_ENS : 1;
    u16* h0 = (u16*)alloc((size_t)MC * BATCH * HID * 2);
    u16* h1 = (u16*)alloc((size_t)MC * BATCH * HID * 2);

    // ---- prep ----
    {
        int total = BATCH * KP / 2;
        build_x<<<(total + 255) / 256, 256, 0, stream>>>(z_hist, a_hist, xp);
        dim3 g1(KP / 32, HID / 32, M_ENS);
        transpose_cvt<<<g1, 256, 0, stream>>>(W1, W1t, DIN, HID, KP);
        dim3 g2(HID / 32, HID / 32, NHL * M_ENS);
        transpose_cvt<<<g2, 256, 0, stream>>>(Wh, Wht, HID, HID, HID);
        dim3 g3(HID / 32, LDIM / 32, M_ENS);
        transpose_cvt<<<g3, 256, 0, stream>>>(W3, W3t, HID, LDIM, HID);
        int n = NHL * M_ENS * HID;
        make_tables<<<(n + 255) / 256, 256, 0, stream>>>(bh, gamma, beta, rmean, rvar, stab, ttab, n);
    }

    if (full) {
        (void)hipFuncSetAttribute(reinterpret_cast<const void*>(&gemm8p<0>),
                                  hipFuncAttributeMaxDynamicSharedMemorySize, 131072);
        (void)hipFuncSetAttribute(reinterpret_cast<const void*>(&gemm8p<1>),
                                  hipFuncAttributeMaxDynamicSharedMemorySize, 131072);
        // layer 1 fused over ensemble: [B,KP] x [4096,KP]^T -> h0[m][B][HID]
        gemm8p<0><<<1024, 512, 131072, stream>>>(xp, W1t, nullptr, b1, h0, KP);
        // hidden layers (one model per XCD chunk)
        gemm8p<1><<<1024, 512, 131072, stream>>>(h0, Wht, stab, ttab, h1, HID);
        gemm8p<1><<<1024, 512, 131072, stream>>>(h1, Wht + (size_t)M_ENS * HID * HID,
                                                 stab + M_ENS * HID, ttab + M_ENS * HID, h0, HID);
        // output layer: h0 * W3t + b3 + z_last -> out (fp32)
        dim3 gridO(BATCH / 128, LDIM / 128, M_ENS);
        gemm_bt<2><<<gridO, 256, 0, stream>>>(
            h0, (size_t)BATCH * HID, HID,
            W3t, (size_t)LDIM * HID,
            nullptr, b3, LDIM,
            nullptr, 0,
            out, (size_t)BATCH * LDIM,
            z_hist,
            HID, 0);
    } else {
        // fallback: round-1 path, chunked over ensemble
        for (int m0 = 0; m0 < M_ENS; m0 += MC) {
            dim3 grid(BATCH / 128, HID / 128, MC);
            gemm_bt<0><<<grid, 256, 0, stream>>>(
                xp, 0, KP,
                W1t + (size_t)m0 * HID * KP, (size_t)HID * KP,
                nullptr, b1, HID,
                h0, (size_t)BATCH * HID, nullptr, 0, nullptr,
                KP, m0);
            for (int l = 0; l < NHL; ++l) {
                u16* hin = l ? h1 : h0;
                u16* hout = l ? h0 : h1;
                gemm_bt<1><<<grid, 256, 0, stream>>>(
                    hin, (size_t)BATCH * HID, HID,
                    Wht + ((size_t)l * M_ENS + m0) * HID * HID, (size_t)HID * HID,
                    stab + (size_t)l * M_ENS * HID, ttab + (size_t)l * M_ENS * HID, HID,
                    hout, (size_t)BATCH * HID, nullptr, 0, nullptr,
                    HID, m0);
            }
            dim3 gridO(BATCH / 128, LDIM / 128, MC);
            gemm_bt<2><<<gridO, 256, 0, stream>>>(
                h0, (size_t)BATCH * HID, HID,
                W3t + (size_t)m0 * LDIM * HID, (size_t)LDIM * HID,
                nullptr, b3, LDIM,
                nullptr, 0,
                out + (size_t)m0 * BATCH * LDIM, (size_t)BATCH * LDIM,
                z_hist,
                HID, 0);
        }
    }
}

// Round 3
// 626.472 us; speedup vs baseline: 1.0534x; 1.0131x over previous
//
#include <hip/hip_runtime.h>
#include <hip/hip_bf16.h>

#define M_ENS 8
#define BATCH 16384
#define HIST 5
#define LDIM 384
#define HID 512
#define NHL 2
#define DIN 1925
#define KP 2048   // DIN padded to multiple of 128

typedef unsigned short u16;
typedef unsigned int u32;
typedef __attribute__((ext_vector_type(8))) short bf16x8;
typedef __attribute__((ext_vector_type(4))) float f32x4;

__device__ __forceinline__ u16 f2b(float f) {
    u32 u = __builtin_bit_cast(u32, f);
    u32 r = (u + 0x7fffu + ((u >> 16) & 1u)) >> 16;
    return (u16)r;
}

#define BARRIER asm volatile("s_barrier" ::: "memory")

// ---------------- prep: build padded bf16 x = concat(z_hist, a_hist) ----------------
__global__ void build_x(const float* __restrict__ z, const float* __restrict__ a,
                        u16* __restrict__ xp) {
    int idx = blockIdx.x * 256 + threadIdx.x;
    int b = idx / (KP / 2);
    int k2 = (idx % (KP / 2)) * 2;
    if (b >= BATCH) return;
    u32 packed = 0;
#pragma unroll
    for (int j = 0; j < 2; ++j) {
        int k = k2 + j;
        float v = 0.f;
        if (k < HIST * LDIM) v = z[(size_t)b * (HIST * LDIM) + k];
        else if (k < DIN)    v = a[b * HIST + (k - HIST * LDIM)];
        packed |= ((u32)f2b(v)) << (16 * j);
    }
    *(u32*)(&xp[(size_t)b * KP + k2]) = packed;
}

// ---------------- prep: fp32 [R][C] -> bf16 [C][Rp] transpose+convert ----------------
__global__ void transpose_cvt(const float* __restrict__ in, u16* __restrict__ out,
                              int R, int C, int Rp) {
    __shared__ float tile[32][33];
    const float* inb = in + (size_t)blockIdx.z * R * C;
    u16* outb = out + (size_t)blockIdx.z * C * Rp;
    int r0 = blockIdx.x * 32, c0 = blockIdx.y * 32;
    int tx = threadIdx.x & 31, ty = threadIdx.x >> 5;
#pragma unroll
    for (int i = 0; i < 32; i += 8) {
        int r = r0 + ty + i;
        float v = 0.f;
        if (r < R) v = inb[(size_t)r * C + c0 + tx];
        tile[ty + i][tx] = v;
    }
    __syncthreads();
#pragma unroll
    for (int i = 0; i < 32; i += 8) {
        outb[(size_t)(c0 + ty + i) * Rp + r0 + tx] = f2b(tile[tx][ty + i]);
    }
}

// ---------------- prep: fold BN into scale/shift ----------------
__global__ void make_tables(const float* __restrict__ bh, const float* __restrict__ gamma,
                            const float* __restrict__ beta, const float* __restrict__ rmean,
                            const float* __restrict__ rvar, float* __restrict__ s,
                            float* __restrict__ t, int n) {
    int i = blockIdx.x * 256 + threadIdx.x;
    if (i >= n) return;
    float inv = rsqrtf(rvar[i] + 1e-5f);
    float sc = gamma[i] * inv;
    s[i] = sc;
    t[i] = (bh[i] - rmean[i]) * sc + beta[i];
}

// =====================================================================================
// 8-phase 256x256 GEMM (T3+T4 counted vmcnt, T5 setprio), BK=64, 8 waves (2M x 4N).
// MODE 0: fused layer1; XCD owns a COLUMN-chunk (2 colTs -> B L2-resident)
// MODE 1: hidden layer; one model per XCD (weights L2-resident)
// =====================================================================================
template <int MODE>
__global__ __launch_bounds__(512, 2) void gemm8p(
    const u16* __restrict__ A, const u16* __restrict__ Bw,
    const float* __restrict__ Sv, const float* __restrict__ Tv,
    u16* __restrict__ Ho, int K) {
    extern __shared__ char smem[];
    const int tid = threadIdx.x;
    const int lane = tid & 63;
    const int wid = tid >> 6;
    const int wm = wid >> 2;
    const int wn = wid & 3;

    int rowT, colT, mI;
    const u16 *Ab, *Bb;
    int lda, ldb;
    if (MODE == 0) {
        // column-chunk per XCD: B panel (2 x 1MB) stays L2-resident; rowT sweeps.
        int xcd = blockIdx.x & 7, i = blockIdx.x >> 3;
        rowT = i >> 1; colT = xcd * 2 + (i & 1);
        Ab = A; lda = KP;
        Bb = Bw + (size_t)colT * 256 * KP; ldb = KP;
        mI = 0;
    } else {
        const int nwg = gridDim.x;
        const int swz = (blockIdx.x & 7) * (nwg >> 3) + (blockIdx.x >> 3);
        mI = swz >> 7;
        int rem = swz & 127;
        rowT = rem >> 1; colT = rem & 1;
        Ab = A + (size_t)mI * BATCH * HID; lda = HID;
        Bb = Bw + (size_t)mI * HID * HID + (size_t)colT * 256 * HID; ldb = HID;
    }
    const int rowBase = rowT * 256;
    const int NT = K >> 6;

    auto STAGE = [&](int par, int op, int half, int tk) {
#pragma unroll
        for (int i = 0; i < 2; ++i) {
            int ii = wid * 2 + i;
            int row = ii * 8 + (lane >> 3);
            int gc = lane & 7;
            const u16* src;
            if (op == 0)
                src = Ab + (size_t)(rowBase + half * 128 + row) * lda + tk * 64 + ((gc ^ (row & 7)) << 3);
            else
                src = Bb + (size_t)(half * 128 + row) * ldb + tk * 64 + ((gc ^ (row & 7)) << 3);
            u16* dst = (u16*)(smem + par * 65536 + op * 32768 + half * 16384) + (size_t)(ii * 64 + lane) * 8;
            __builtin_amdgcn_global_load_lds((const __attribute__((address_space(1))) void*)src,
                                             (__attribute__((address_space(3))) void*)dst, 16, 0, 0);
        }
    };

    const int laneRow = lane & 15;
    int xg[2];
    xg[0] = (((lane >> 4)) ^ (lane & 7)) << 4;
    xg[1] = ((4 | (lane >> 4)) ^ (lane & 7)) << 4;
#define RDF(base, r, kk) (*(const bf16x8*)((base) + (size_t)(r) * 128 + xg[kk]))

    f32x4 acc[8][4] = {};
    bf16x8 af[4][2], bfr[4][2];
    const int bcol0 = (wn & 1) * 64;

    STAGE(0, 1, 0, 0); STAGE(0, 1, 1, 0);
    STAGE(0, 0, 0, 0); STAGE(0, 0, 1, 0);
    if (NT > 1) { STAGE(1, 1, 0, 1); STAGE(1, 1, 1, 1); }
    asm volatile("s_waitcnt vmcnt(4)" ::: "memory");
    BARRIER;

    for (int T = 0; T < NT; ++T) {
        const int p = T & 1;
        const char* pA = smem + p * 65536 + wm * 16384;
        const char* pB = smem + p * 65536 + 32768 + (wn >> 1) * 16384;

#pragma unroll
        for (int mf = 0; mf < 4; ++mf) {
            af[mf][0] = RDF(pA, mf * 16 + laneRow, 0);
            af[mf][1] = RDF(pA, mf * 16 + laneRow, 1);
        }
#pragma unroll
        for (int nf = 0; nf < 2; ++nf) {
            bfr[nf][0] = RDF(pB, bcol0 + nf * 16 + laneRow, 0);
            bfr[nf][1] = RDF(pB, bcol0 + nf * 16 + laneRow, 1);
        }
        if (T + 1 < NT) STAGE((T + 1) & 1, 0, 0, T + 1);
        BARRIER;
        __builtin_amdgcn_s_setprio(1);
#pragma unroll
        for (int kk = 0; kk < 2; ++kk)
#pragma unroll
            for (int mf = 0; mf < 4; ++mf)
#pragma unroll
                for (int nf = 0; nf < 2; ++nf)
                    acc[mf][nf] = __builtin_amdgcn_mfma_f32_16x16x32_bf16(af[mf][kk], bfr[nf][kk], acc[mf][nf], 0, 0, 0);
        __builtin_amdgcn_s_setprio(0);
        BARRIER;

#pragma unroll
        for (int nf = 2; nf < 4; ++nf) {
            bfr[nf][0] = RDF(pB, bcol0 + nf * 16 + laneRow, 0);
            bfr[nf][1] = RDF(pB, bcol0 + nf * 16 + laneRow, 1);
        }
        if (T + 1 < NT) STAGE((T + 1) & 1, 0, 1, T + 1);
        BARRIER;
        __builtin_amdgcn_s_setprio(1);
#pragma unroll
        for (int kk = 0; kk < 2; ++kk)
#pragma unroll
            for (int mf = 0; mf < 4; ++mf)
#pragma unroll
                for (int nf = 2; nf < 4; ++nf)
                    acc[mf][nf] = __builtin_amdgcn_mfma_f32_16x16x32_bf16(af[mf][kk], bfr[nf][kk], acc[mf][nf], 0, 0, 0);
        __builtin_amdgcn_s_setprio(0);
        BARRIER;

#pragma unroll
        for (int mf = 0; mf < 4; ++mf) {
            af[mf][0] = RDF(pA, (4 + mf) * 16 + laneRow, 0);
            af[mf][1] = RDF(pA, (4 + mf) * 16 + laneRow, 1);
        }
        if (T + 2 < NT) STAGE(p, 1, 0, T + 2);
        BARRIER;
        __builtin_amdgcn_s_setprio(1);
#pragma unroll
        for (int kk = 0; kk < 2; ++kk)
#pragma unroll
            for (int mf = 0; mf < 4; ++mf)
#pragma unroll
                for (int nf = 2; nf < 4; ++nf)
                    acc[4 + mf][nf] = __builtin_amdgcn_mfma_f32_16x16x32_bf16(af[mf][kk], bfr[nf][kk], acc[4 + mf][nf], 0, 0, 0);
        __builtin_amdgcn_s_setprio(0);
        BARRIER;

        if (T + 2 < NT) {
            STAGE(p, 1, 1, T + 2);
            asm volatile("s_waitcnt vmcnt(4)" ::: "memory");
        } else {
            asm volatile("s_waitcnt vmcnt(0)" ::: "memory");
        }
        BARRIER;
        __builtin_amdgcn_s_setprio(1);
#pragma unroll
        for (int kk = 0; kk < 2; ++kk)
#pragma unroll
            for (int mf = 0; mf < 4; ++mf)
#pragma unroll
                for (int nf = 0; nf < 2; ++nf)
                    acc[4 + mf][nf] = __builtin_amdgcn_mfma_f32_16x16x32_bf16(af[mf][kk], bfr[nf][kk], acc[4 + mf][nf], 0, 0, 0);
        __builtin_amdgcn_s_setprio(0);
        BARRIER;
    }

#pragma unroll
    for (int mf = 0; mf < 8; ++mf) {
        int row = rowBase + wm * 128 + mf * 16 + ((lane >> 4) << 2);
#pragma unroll
        for (int nf = 0; nf < 4; ++nf) {
            int c = colT * 256 + wn * 64 + nf * 16 + (lane & 15);
            if (MODE == 0) {
                float tb = Tv[c];
                size_t base = (size_t)(c >> 9) * BATCH * HID + (c & 511);
#pragma unroll
                for (int q = 0; q < 4; ++q) {
                    float v = acc[mf][nf][q] + tb;
                    Ho[base + (size_t)(row + q) * HID] = f2b(v > 0.f ? v : 0.f);
                }
            } else {
                float sc = Sv[mI * HID + c], tb = Tv[mI * HID + c];
                u16* H = Ho + (size_t)mI * BATCH * HID;
#pragma unroll
                for (int q = 0; q < 4; ++q) {
                    float v = acc[mf][nf][q] * sc + tb;
                    H[(size_t)(row + q) * HID + c] = f2b(v > 0.f ? v : 0.f);
                }
            }
        }
    }
}

// =====================================================================================
// Fused hidden-2 + output: block = 128 rows x one model (model = XCD -> weights in L2).
// LDS 160 KiB: A dbuf 2x16K @0 | B dbuf 2x64K @32K. After hidden-2: h2[128][512] @32K
// (128K), W3 single-buffer [384][32] @0 (reg-staged). h2 never touches HBM.
// =====================================================================================
__global__ __launch_bounds__(512, 1) void h2out(
    const u16* __restrict__ h1, const u16* __restrict__ Wh2,
    const float* __restrict__ Sv, const float* __restrict__ Tv,
    const u16* __restrict__ W3p, const float* __restrict__ b3,
    const float* __restrict__ zres, float* __restrict__ out) {
    extern __shared__ char smem[];
    const int tid = threadIdx.x;
    const int lane = tid & 63;
    const int wid = tid >> 6;
    const int wm = wid >> 2;          // 0..1: 64-row half
    const int wn = wid & 3;           // 0..3: 128-col quarter
    const int m = blockIdx.x & 7;
    const int rowBase = (blockIdx.x >> 3) * 128;
    const int lr15 = lane & 15;

    const u16* Ab = h1 + ((size_t)m * BATCH + rowBase) * HID;
    const u16* Bb = Wh2 + (size_t)m * HID * HID;
    const u16* W3b = W3p + (size_t)m * LDIM * HID;
    const float* b3b = b3 + m * LDIM;

    int xg[2];
    xg[0] = (((lane >> 4)) ^ (lane & 7)) << 4;
    xg[1] = ((4 | (lane >> 4)) ^ (lane & 7)) << 4;

    auto stA = [&](int par, int tk) {
#pragma unroll
        for (int i = 0; i < 2; ++i) {
            int ii = wid * 2 + i;
            int row = ii * 8 + (lane >> 3);
            int gc = lane & 7;
            const u16* src = Ab + (size_t)row * HID + tk * 64 + ((gc ^ (row & 7)) << 3);
            u16* dst = (u16*)(smem + par * 16384) + (size_t)(ii * 64 + lane) * 8;
            __builtin_amdgcn_global_load_lds((const __attribute__((address_space(1))) void*)src,
                                             (__attribute__((address_space(3))) void*)dst, 16, 0, 0);
        }
    };
    auto stB = [&](int par, int q, int tk) {
#pragma unroll
        for (int i = 0; i < 2; ++i) {
            int ii = wid * 2 + i;
            int row = ii * 8 + (lane >> 3);
            int gc = lane & 7;
            const u16* src = Bb + (size_t)(q * 128 + row) * HID + tk * 64 + ((gc ^ (row & 7)) << 3);
            u16* dst = (u16*)(smem + 32768 + par * 65536 + q * 16384) + (size_t)(ii * 64 + lane) * 8;
            __builtin_amdgcn_global_load_lds((const __attribute__((address_space(1))) void*)src,
                                             (__attribute__((address_space(3))) void*)dst, 16, 0, 0);
        }
    };

    // ---- hidden-2: 4-phase, counted vmcnt ----
    f32x4 acc[4][8] = {};
    bf16x8 afr[4][2];
    const int NT = HID / 64;   // 8

    stA(0, 0); stB(0, 0, 0); stB(0, 1, 0); stB(0, 2, 0); stB(0, 3, 0);
    asm volatile("s_waitcnt vmcnt(0)" ::: "memory");
    BARRIER;

    for (int T = 0; T < NT; ++T) {
        const int p = T & 1;
        const char* pA = smem + p * 16384;
        const char* qb = smem + 32768 + p * 65536 + wn * 16384;

        // ph0: read A (all) + B nf0-1; stage A(T+1)
#pragma unroll
        for (int mf = 0; mf < 4; ++mf) {
            int lr = wm * 64 + mf * 16 + lr15;
            afr[mf][0] = RDF(pA, lr, 0);
            afr[mf][1] = RDF(pA, lr, 1);
        }
        bf16x8 b01[2][2];
#pragma unroll
        for (int nf = 0; nf < 2; ++nf) {
            b01[nf][0] = RDF(qb, nf * 16 + lr15, 0);
            b01[nf][1] = RDF(qb, nf * 16 + lr15, 1);
        }
        if (T + 1 < NT) stA(p ^ 1, T + 1);
        BARRIER;
        __builtin_amdgcn_s_setprio(1);
#pragma unroll
        for (int kk = 0; kk < 2; ++kk)
#pragma unroll
            for (int mf = 0; mf < 4; ++mf)
#pragma unroll
                for (int nf = 0; nf < 2; ++nf)
                    acc[mf][nf] = __builtin_amdgcn_mfma_f32_16x16x32_bf16(afr[mf][kk], b01[nf][kk], acc[mf][nf], 0, 0, 0);
        __builtin_amdgcn_s_setprio(0);
        BARRIER;

        // ph1: read B nf2-3; stage B q0,q1(T+1)
#pragma unroll
        for (int nf = 0; nf < 2; ++nf) {
            b01[nf][0] = RDF(qb, (2 + nf) * 16 + lr15, 0);
            b01[nf][1] = RDF(qb, (2 + nf) * 16 + lr15, 1);
        }
        if (T + 1 < NT) { stB(p ^ 1, 0, T + 1); stB(p ^ 1, 1, T + 1); }
        BARRIER;
        __builtin_amdgcn_s_setprio(1);
#pragma unroll
        for (int kk = 0; kk < 2; ++kk)
#pragma unroll
            for (int mf = 0; mf < 4; ++mf)
#pragma unroll
                for (int nf = 0; nf < 2; ++nf)
                    acc[mf][2 + nf] = __builtin_amdgcn_mfma_f32_16x16x32_bf16(afr[mf][kk], b01[nf][kk], acc[mf][2 + nf], 0, 0, 0);
        __builtin_amdgcn_s_setprio(0);
        BARRIER;

        // ph2: read B nf4-5; stage B q2,q3(T+1)
#pragma unroll
        for (int nf = 0; nf < 2; ++nf) {
            b01[nf][0] = RDF(qb, (4 + nf) * 16 + lr15, 0);
            b01[nf][1] = RDF(qb, (4 + nf) * 16 + lr15, 1);
        }
        if (T + 1 < NT) { stB(p ^ 1, 2, T + 1); stB(p ^ 1, 3, T + 1); }
        BARRIER;
        __builtin_amdgcn_s_setprio(1);
#pragma unroll
        for (int kk = 0; kk < 2; ++kk)
#pragma unroll
            for (int mf = 0; mf < 4; ++mf)
#pragma unroll
                for (int nf = 0; nf < 2; ++nf)
                    acc[mf][4 + nf] = __builtin_amdgcn_mfma_f32_16x16x32_bf16(afr[mf][kk], b01[nf][kk], acc[mf][4 + nf], 0, 0, 0);
        __builtin_amdgcn_s_setprio(0);
        BARRIER;

        // ph3: read B nf6-7; stage A(T+2); counted wait
#pragma unroll
        for (int nf = 0; nf < 2; ++nf) {
            b01[nf][0] = RDF(qb, (6 + nf) * 16 + lr15, 0);
            b01[nf][1] = RDF(qb, (6 + nf) * 16 + lr15, 1);
        }
        if (T + 2 < NT) {
            stA(p, T + 2);
            asm volatile("s_waitcnt vmcnt(2)" ::: "memory");
        } else {
            asm volatile("s_waitcnt vmcnt(0)" ::: "memory");
        }
        BARRIER;
        __builtin_amdgcn_s_setprio(1);
#pragma unroll
        for (int kk = 0; kk < 2; ++kk)
#pragma unroll
            for (int mf = 0; mf < 4; ++mf)
#pragma unroll
                for (int nf = 0; nf < 2; ++nf)
                    acc[mf][6 + nf] = __builtin_amdgcn_mfma_f32_16x16x32_bf16(afr[mf][kk], b01[nf][kk], acc[mf][6 + nf], 0, 0, 0);
        __builtin_amdgcn_s_setprio(0);
        BARRIER;
    }

    // ---- BN+relu, h2 -> LDS @32768 as [128 rows][512 cols], granule-swizzled ----
#pragma unroll
    for (int mf = 0; mf < 4; ++mf) {
#pragma unroll
        for (int nf = 0; nf < 8; ++nf) {
            int col = wn * 128 + nf * 16 + lr15;
            float sc = Sv[m * HID + col], tt = Tv[m * HID + col];
#pragma unroll
            for (int q = 0; q < 4; ++q) {
                int row = wm * 64 + mf * 16 + ((lane >> 4) << 2) + q;
                float v = acc[mf][nf][q] * sc + tt;
                v = v > 0.f ? v : 0.f;
                *(u16*)(smem + 32768 + row * 1024 + (((col >> 3) ^ (row & 7)) << 4) + ((col & 7) << 1)) = f2b(v);
            }
        }
    }
    asm volatile("s_waitcnt lgkmcnt(0)" ::: "memory");
    BARRIER;

    // ---- output layer: K=512 in 16 steps of 32; W3 reg-staged into 24K buffer @0 ----
    bf16x8 w3r[3];
#pragma unroll
    for (int j = 0; j < 3; ++j) {
        int gi = tid * 3 + j;
        w3r[j] = *(const bf16x8*)(W3b + (size_t)(gi >> 2) * HID + ((gi & 3) << 3));
    }
    f32x4 acc2[4][6] = {};
    for (int t = 0; t < 16; ++t) {
#pragma unroll
        for (int j = 0; j < 3; ++j) {
            int gi = tid * 3 + j;
            *(bf16x8*)(smem + (gi >> 2) * 64 + (((gi & 3) ^ ((gi >> 2) & 3)) << 4)) = w3r[j];
        }
        if (t + 1 < 16) {
#pragma unroll
            for (int j = 0; j < 3; ++j) {
                int gi = tid * 3 + j;
                w3r[j] = *(const bf16x8*)(W3b + (size_t)(gi >> 2) * HID + (t + 1) * 32 + ((gi & 3) << 3));
            }
        }
        asm volatile("s_waitcnt lgkmcnt(0)" ::: "memory");
        BARRIER;
        bf16x8 a1[4], b1r[6];
#pragma unroll
        for (int mf = 0; mf < 4; ++mf) {
            int r = wm * 64 + mf * 16 + lr15;
            a1[mf] = *(const bf16x8*)(smem + 32768 + r * 1024 + (((4 * t + (lane >> 4)) ^ (lane & 7)) << 4));
        }
#pragma unroll
        for (int nf = 0; nf < 6; ++nf) {
            int r3 = wn * 96 + nf * 16 + lr15;
            b1r[nf] = *(const bf16x8*)(smem + r3 * 64 + (((lane >> 4) ^ (r3 & 3)) << 4));
        }
        __builtin_amdgcn_s_setprio(1);
#pragma unroll
        for (int mf = 0; mf < 4; ++mf)
#pragma unroll
            for (int nf = 0; nf < 6; ++nf)
                acc2[mf][nf] = __builtin_amdgcn_mfma_f32_16x16x32_bf16(a1[mf], b1r[nf], acc2[mf][nf], 0, 0, 0);
        __builtin_amdgcn_s_setprio(0);
        BARRIER;
    }

#pragma unroll
    for (int mf = 0; mf < 4; ++mf) {
#pragma unroll
        for (int nf = 0; nf < 6; ++nf) {
            int c = wn * 96 + nf * 16 + lr15;
            float bv = b3b[c];
#pragma unroll
            for (int q = 0; q < 4; ++q) {
                int grow = rowBase + wm * 64 + mf * 16 + ((lane >> 4) << 2) + q;
                out[((size_t)m * BATCH + grow) * LDIM + c] =
                    acc2[mf][nf][q] + bv + zres[(size_t)grow * (HIST * LDIM) + (HIST - 1) * LDIM + c];
            }
        }
    }
}

// ---------------- 128x128 m97-structure GEMM (fallback path) ----------------
template <int MODE>
__global__ __launch_bounds__(256, 2) void gemm_bt(
    const u16* __restrict__ A, size_t aStride, int lda,
    const u16* __restrict__ Bt, size_t bStride,
    const float* __restrict__ Sv, const float* __restrict__ Tv, int ptStride,
    u16* __restrict__ Ho, size_t hStride,
    float* __restrict__ Fo, size_t fStride,
    const float* __restrict__ Zres,
    int K, int m0) {
    __shared__ u16 As[128 * 64];
    __shared__ u16 Bs[128 * 64];

    const int tid = threadIdx.x;
    const int lane = tid & 63;
    const int wid = tid >> 6;
    const int wr = (wid >> 1) * 64;
    const int wc = (wid & 1) * 64;
    const int z = blockIdx.z;
    const int rowBase = blockIdx.x * 128;
    const int colBase = blockIdx.y * 128;

    const u16* Ab = A + (size_t)z * aStride;
    const u16* Bb = Bt + (size_t)z * bStride;

    f32x4 acc[4][4] = {};

    int aoff[4], boff[4];
#pragma unroll
    for (int f = 0; f < 4; ++f) {
        int ar = wr + f * 16 + (lane & 15);
        aoff[f] = (ar * 128 + ((lane >> 4) * 16)) ^ ((ar & 7) << 4);
        int br = wc + f * 16 + (lane & 15);
        boff[f] = (br * 128 + ((lane >> 4) * 16)) ^ ((br & 7) << 4);
    }

    for (int k0 = 0; k0 < K; k0 += 64) {
#pragma unroll
        for (int i = 0; i < 4; ++i) {
            int gg = i * 256 + tid;
            int row = gg >> 3, gc = gg & 7;
            const u16* srcA = Ab + (size_t)(rowBase + row) * lda + k0 + ((gc ^ (row & 7)) << 3);
            __builtin_amdgcn_global_load_lds(
                (const __attribute__((address_space(1))) void*)srcA,
                (__attribute__((address_space(3))) void*)(As + gg * 8), 16, 0, 0);
            const u16* srcB = Bb + (size_t)(colBase + row) * K + k0 + ((gc ^ (row & 7)) << 3);
            __builtin_amdgcn_global_load_lds(
                (const __attribute__((address_space(1))) void*)srcB,
                (__attribute__((address_space(3))) void*)(Bs + gg * 8), 16, 0, 0);
        }
        __syncthreads();
#pragma unroll
        for (int kk = 0; kk < 2; ++kk) {
            bf16x8 af[4], bfr[4];
#pragma unroll
            for (int f = 0; f < 4; ++f) {
                af[f]  = *(const bf16x8*)((const char*)As + (aoff[f] ^ (kk << 6)));
                bfr[f] = *(const bf16x8*)((const char*)Bs + (boff[f] ^ (kk << 6)));
            }
#pragma unroll
            for (int i = 0; i < 4; ++i)
#pragma unroll
                for (int j = 0; j < 4; ++j)
                    acc[i][j] = __builtin_amdgcn_mfma_f32_16x16x32_bf16(af[i], bfr[j], acc[i][j], 0, 0, 0);
        }
        __syncthreads();
    }

    const int mg = m0 + z;
#pragma unroll
    for (int i = 0; i < 4; ++i) {
        int rbase = rowBase + wr + i * 16 + ((lane >> 4) << 2);
#pragma unroll
        for (int j = 0; j < 4; ++j) {
            int n = colBase + wc + j * 16 + (lane & 15);
            if (MODE == 0) {
                float bias = Tv[(size_t)mg * ptStride + n];
                u16* H = Ho + (size_t)z * hStride;
#pragma unroll
                for (int q = 0; q < 4; ++q) {
                    float v = acc[i][j][q] + bias;
                    v = v > 0.f ? v : 0.f;
                    H[(size_t)(rbase + q) * HID + n] = f2b(v);
                }
            } else if (MODE == 1) {
                float sc = Sv[(size_t)mg * ptStride + n];
                float tt = Tv[(size_t)mg * ptStride + n];
                u16* H = Ho + (size_t)z * hStride;
#pragma unroll
                for (int q = 0; q < 4; ++q) {
                    float v = acc[i][j][q] * sc + tt;
                    v = v > 0.f ? v : 0.f;
                    H[(size_t)(rbase + q) * HID + n] = f2b(v);
                }
            } else {
                float bias = Tv[(size_t)mg * ptStride + n];
                float* F = Fo + (size_t)z * fStride;
#pragma unroll
                for (int q = 0; q < 4; ++q) {
                    int b = rbase + q;
                    float v = acc[i][j][q] + bias + Zres[(size_t)b * (HIST * LDIM) + (HIST - 1) * LDIM + n];
                    F[(size_t)b * LDIM + n] = v;
                }
            }
        }
    }
}

extern "C" void kernel_launch(void* const* d_in, const int* in_sizes, int n_in,
                              void* d_out, int out_size, void* d_ws, size_t ws_size,
                              hipStream_t stream) {
    const float* z_hist = (const float*)d_in[0];
    const float* a_hist = (const float*)d_in[1];
    const float* W1    = (const float*)d_in[2];
    const float* b1    = (const float*)d_in[3];
    const float* Wh    = (const float*)d_in[4];
    const float* bh    = (const float*)d_in[5];
    const float* gamma = (const float*)d_in[6];
    const float* beta  = (const float*)d_in[7];
    const float* rmean = (const float*)d_in[8];
    const float* rvar  = (const float*)d_in[9];
    const float* W3    = (const float*)d_in[10];
    const float* b3    = (const float*)d_in[11];
    float* out = (float*)d_out;

    char* ws = (char*)d_ws;
    size_t off = 0;
    auto alloc = [&](size_t bytes) {
        void* p = ws + off;
        off = (off + bytes + 255) & ~(size_t)255;
        return p;
    };
    u16* xp  = (u16*)alloc((size_t)BATCH * KP * 2);
    u16* W1t = (u16*)alloc((size_t)M_ENS * HID * KP * 2);
    u16* Wht = (u16*)alloc((size_t)NHL * M_ENS * HID * HID * 2);
    u16* W3t = (u16*)alloc((size_t)M_ENS * LDIM * HID * 2);
    float* stab = (float*)alloc((size_t)NHL * M_ENS * HID * 4);
    float* ttab = (float*)alloc((size_t)NHL * M_ENS * HID * 4);
    size_t fixed = off;
    size_t hFull = (size_t)M_ENS * BATCH * HID * 2;
    bool full = (fixed + 2 * hFull <= ws_size);
    int MC = full ? M_ENS : 1;
    u16* h0 = (u16*)alloc((size_t)MC * BATCH * HID * 2);
    u16* h1 = (u16*)alloc((size_t)MC * BATCH * HID * 2);

    // ---- prep ----
    {
        int total = BATCH * KP / 2;
        build_x<<<(total + 255) / 256, 256, 0, stream>>>(z_hist, a_hist, xp);
        dim3 g1(KP / 32, HID / 32, M_ENS);
        transpose_cvt<<<g1, 256, 0, stream>>>(W1, W1t, DIN, HID, KP);
        dim3 g2(HID / 32, HID / 32, NHL * M_ENS);
        transpose_cvt<<<g2, 256, 0, stream>>>(Wh, Wht, HID, HID, HID);
        dim3 g3(HID / 32, LDIM / 32, M_ENS);
        transpose_cvt<<<g3, 256, 0, stream>>>(W3, W3t, HID, LDIM, HID);
        int n = NHL * M_ENS * HID;
        make_tables<<<(n + 255) / 256, 256, 0, stream>>>(bh, gamma, beta, rmean, rvar, stab, ttab, n);
    }

    if (full) {
        (void)hipFuncSetAttribute(reinterpret_cast<const void*>(&gemm8p<0>),
                                  hipFuncAttributeMaxDynamicSharedMemorySize, 131072);
        (void)hipFuncSetAttribute(reinterpret_cast<const void*>(&gemm8p<1>),
                                  hipFuncAttributeMaxDynamicSharedMemorySize, 131072);
        (void)hipFuncSetAttribute(reinterpret_cast<const void*>(&h2out),
                                  hipFuncAttributeMaxDynamicSharedMemorySize, 163840);
        // layer 1 fused over ensemble
        gemm8p<0><<<1024, 512, 131072, stream>>>(xp, W1t, nullptr, b1, h0, KP);
        // hidden layer 0
        gemm8p<1><<<1024, 512, 131072, stream>>>(h0, Wht, stab, ttab, h1, HID);
        // fused hidden layer 1 + output (+residual)
        h2out<<<1024, 512, 163840, stream>>>(
            h1, Wht + (size_t)M_ENS * HID * HID,
            stab + M_ENS * HID, ttab + M_ENS * HID,
            W3t, b3, z_hist, out);
    } else {
        for (int m0 = 0; m0 < M_ENS; m0 += MC) {
            dim3 grid(BATCH / 128, HID / 128, MC);
            gemm_bt<0><<<grid, 256, 0, stream>>>(
                xp, 0, KP,
                W1t + (size_t)m0 * HID * KP, (size_t)HID * KP,
                nullptr, b1, HID,
                h0, (size_t)BATCH * HID, nullptr, 0, nullptr,
                KP, m0);
            for (int l = 0; l < NHL; ++l) {
                u16* hin = l ? h1 : h0;
                u16* hout = l ? h0 : h1;
                gemm_bt<1><<<grid, 256, 0, stream>>>(
                    hin, (size_t)BATCH * HID, HID,
                    Wht + ((size_t)l * M_ENS + m0) * HID * HID, (size_t)HID * HID,
                    stab + (size_t)l * M_ENS * HID, ttab + (size_t)l * M_ENS * HID, HID,
                    hout, (size_t)BATCH * HID, nullptr, 0, nullptr,
                    HID, m0);
            }
            dim3 gridO(BATCH / 128, LDIM / 128, MC);
            gemm_bt<2><<<gridO, 256, 0, stream>>>(
                h0, (size_t)BATCH * HID, HID,
                W3t + (size_t)m0 * LDIM * HID, (size_t)LDIM * HID,
                nullptr, b3, LDIM,
                nullptr, 0,
                out + (size_t)m0 * BATCH * LDIM, (size_t)BATCH * LDIM,
                z_hist,
                HID, m0);
        }
    }
}